// Round 12
// baseline (4125.667 us; speedup 1.0000x reference)
//
#include <hip/hip_runtime.h>

// Problem constants (DiffeqSolver: S=1, b=64, N=50, F=64, H=128, K=2, T=40)
#define B_   64
#define N_   50
#define F_   64
#define H_   128
#define T_   40
#define E_   2450      // N*(N-1)
#define EPN  49        // edges per receiving node
#define NGRP 25        // node-groups per batch (2 nodes each)
#define EVAL_BLOCKS (B_ * NGRP)   // 1600

typedef __attribute__((ext_vector_type(8))) short  short8;   // 8 x bf16 (4 VGPRs)
typedef __attribute__((ext_vector_type(4))) float  float4_;  // MFMA accumulator

__device__ __forceinline__ unsigned short f2bf(float x) {
    union { float f; unsigned u; } v; v.f = x;
    unsigned r = v.u + 0x7fffu + ((v.u >> 16) & 1u);   // round-to-nearest-even
    return (unsigned short)(r >> 16);
}
__device__ __forceinline__ float bf2f(unsigned short x) {
    union { unsigned u; float f; } v; v.u = ((unsigned)x) << 16;
    return v.f;
}
// HW pack: 2 f32 -> 2 bf16 (RNE), one VALU op (no builtin on gfx950; verified
// numerically identical to manual f2bf pair in round 8 — absmax unchanged)
__device__ __forceinline__ unsigned cvtpk_bf16(float lo, float hi) {
    unsigned r;
    asm("v_cvt_pk_bf16_f32 %0, %1, %2" : "=v"(r) : "v"(lo), "v"(hi));
    return r;
}

// ---------------------------------------------------------------------------
// Setup: w2f = W2 in MFMA-fragment order (1KB contiguous per wave fragment).
// ---------------------------------------------------------------------------
__global__ void k_w2f(const float* __restrict__ W2, unsigned short* __restrict__ w2f) {
    int tid = blockIdx.x * 256 + threadIdx.x;   // 0 .. 32767
    int chunk = tid >> 9, lane = (tid >> 3) & 63, e = tid & 7;
    int ctile = chunk >> 3, ty = (chunk >> 2) & 1, kc = chunk & 3;
    int i = (kc << 5) + ((lane >> 4) << 3) + e;     // W2 row (k)
    int j = (ctile << 4) + (lane & 15);             // W2 col
    w2f[tid] = f2bf(W2[(((ty << 7) | i) << 7) | j]);
}

// Setup: wcf = W1-concat in fragment order (for G production).
__global__ void k_wcf(const float* __restrict__ W1, unsigned short* __restrict__ wcf) {
    int tid = blockIdx.x * 256 + threadIdx.x;   // 0 .. 32767
    int chunk2 = tid >> 9, lane = (tid >> 3) & 63, e = tid & 7;
    int c = chunk2 >> 1, h = chunk2 & 1;
    int col = (c << 4) + (lane & 15);
    int kk  = (h << 5) + ((lane >> 4) << 3) + e;
    int t = col >> 8, part = (col >> 7) & 1, hcol = col & 127;
    wcf[tid] = f2bf(W1[((t << 7) + (part << 6) + kk) * 128 + hcol]);
}

// Setup: w3f[c][f][e] = bf16(W3[c*8+e][f])
__global__ void k_w3f(const float* __restrict__ W3, unsigned short* __restrict__ w3f) {
    int tid = blockIdx.x * 256 + threadIdx.x;   // 0 .. 8191
    int c = tid >> 9, f = (tid >> 3) & 63, e = tid & 7;
    w3f[tid] = f2bf(W3[(((c << 3) + e) << 6) | f]);
}

// ---------------------------------------------------------------------------
// Setup: per (b, n): counting-sort the 49 senders by edge type.
// ---------------------------------------------------------------------------
__global__ void k_sort(const int* __restrict__ graph, int* __restrict__ slots,
                       int* __restrict__ a0w) {
    int tid = blockIdx.x * 256 + threadIdx.x;
    if (tid >= B_ * N_) return;
    int b = tid / N_, n = tid % N_;
    const int* g = graph + b * E_ + n * EPN;
    int base = tid * 64;
    for (int j = 0; j < 64; j++) slots[base + j] = -1;
    int g0 = 0;
    for (int j = 0; j < EPN; j++) g0 += (g[j] == 0);
    int a0 = (g0 + 15) & ~15;
    int g1 = EPN - g0;
    a0w[tid] = a0 | (g0 << 8) | (g1 << 16);
    int p0 = 0, p1 = a0;
    for (int j = 0; j < EPN; j++) {
        int s = (j < n) ? j : j + 1;        // sender index (skip self-loop)
        if (g[j] == 0) slots[base + (p0++)] = s;
        else           slots[base + (p1++)] = s;
    }
}

// ---------------------------------------------------------------------------
// Setup: Y = first_point (f32 state), yb0 = bf16 mirror, out[:, t=0, :] = y0
// ---------------------------------------------------------------------------
__global__ void k_init(const float* __restrict__ fp, float* __restrict__ Y,
                       unsigned short* __restrict__ yb0, float* __restrict__ out) {
    int tid = blockIdx.x * 256 + threadIdx.x;   // 0 .. 204799
    float v = fp[tid];
    Y[tid] = v;
    yb0[tid] = f2bf(v);
    int bn = tid >> 6, f = tid & 63;
    out[bn * (T_ * F_) + f] = v;
}

// ---------------------------------------------------------------------------
// One-time: G0[node][t][0:128]=HS, [128:256]=HRB (+b1), from yb0.  bf16.
// G layout: ((node*2 + t) * 256 + idx) bf16; node 3200 = zero pad row.
// ---------------------------------------------------------------------------
__global__ void k_ginit(const unsigned short* __restrict__ yb0,
                        const unsigned short* __restrict__ wcf,
                        const float* __restrict__ b1g,
                        unsigned short* __restrict__ G0, unsigned short* __restrict__ G1) {
    int blk = blockIdx.x, tid = threadIdx.x;
    if (blk == 200) {
        for (int i = tid; i < 512; i += 256) {
            G0[3200 * 512 + i] = 0;
            G1[3200 * 512 + i] = 0;
        }
        return;
    }
    int lane = tid & 63, w = tid >> 6, lr = lane & 15, q = lane >> 4;
    int n0 = blk * 16;
    short8 a0v = *(const short8*)(yb0 + (n0 + lr) * 64 + (q << 3));
    short8 a1v = *(const short8*)(yb0 + (n0 + lr) * 64 + 32 + (q << 3));
    const float4_ fz = {0.f, 0.f, 0.f, 0.f};
    #pragma unroll
    for (int ct = 0; ct < 8; ct++) {
        int c  = (w << 3) | ct;              // col-tile 0..31
        int c0 = c << 4;
        short8 bb0 = *(const short8*)(wcf + (c << 10) + (lane << 3));
        short8 bb1 = *(const short8*)(wcf + (c << 10) + 512 + (lane << 3));
        float4_ ag = fz;
        ag = __builtin_amdgcn_mfma_f32_16x16x32_bf16(a0v, bb0, ag, 0, 0, 0);
        ag = __builtin_amdgcn_mfma_f32_16x16x32_bf16(a1v, bb1, ag, 0, 0, 0);
        int ty = c0 >> 8, inner = c0 & 255, part = inner >> 7;
        float bias = part ? b1g[(ty << 7) + (inner & 127) + lr] : 0.f;
        int gbase = (((n0 + (q << 2)) * 2 + ty) << 8) + (part << 7) + (inner & 127) + lr;
        #pragma unroll
        for (int i = 0; i < 4; i++)
            G0[gbase + i * 512] = f2bf(ag[i] + bias);
    }
}

// ---------------------------------------------------------------------------
// One ODE eval + RK4 stage update. Block = (batch b, nodes n0, n0+1).
// Round-11 verified structure (3905 us total) with two critical-path cuts:
//   * slots read directly from global in the build phase (drops the slt
//     staging AND barrier #1; gather loads issue at kernel start)
//   * W3/RK4 phase pair-split across all 256 threads (was 128 active):
//     each lane pair splits the H=128 dot, combined via __shfl_xor(s,1)
// 3 barriers total.  G stored bf16; h packed via v_cvt_pk_bf16_f32.
//
// NOTE: persistent/cooperative variants of this solver are STRUCTURALLY
// WRONG on MI355X — measured twice (rounds 7 & 10): any in-kernel
// device-scope acquire (grid.sync or per-block agent fence) invalidates
// the per-XCD L2 and forces ~46 GB of HBM refetch (40-70 ms).  The 156
// kernel launches ARE the cheap global sync (CP-handled coherence:
// ~3.5 MB fetch/dispatch).
//
// blockIdx remap: batch b pinned to XCD b%8.
// ---------------------------------------------------------------------------
__launch_bounds__(256, 4)
__global__ void k_eval(const unsigned short* __restrict__ Gin,
                       unsigned short* __restrict__ Gout,
                       float* __restrict__ Y, float* __restrict__ ACC,
                       const int* __restrict__ slotsW, const int* __restrict__ a0W,
                       const unsigned short* __restrict__ w2f,
                       const float* __restrict__ b2g,
                       const unsigned short* __restrict__ w3f, const float* __restrict__ b3,
                       const unsigned short* __restrict__ wcf, const float* __restrict__ b1g,
                       const float* __restrict__ ts, float* __restrict__ out,
                       int t, int r) {
    // hraw: 128 rows x 128 bf16, XOR-swizzled (byte ^= (row&7)<<4)
    __shared__ __align__(16) unsigned short hraw[128 * 128];   // 32 KiB
    __shared__ float aggv[2][128];
    __shared__ __align__(16) unsigned short ybnew[2][64];

    const int tid  = threadIdx.x;
    const int lane = tid & 63;
    const int w    = tid >> 6;
    const int blk  = blockIdx.x;
    const int xcd  = blk & 7;
    const int jj   = blk >> 3;               // 0..199
    const int b    = xcd + ((jj / NGRP) << 3);
    const int n0   = (jj % NGRP) * 2;

    int pk0 = a0W[b * N_ + n0], pk1 = a0W[b * N_ + n0 + 1];
    const int a0h0 = pk0 & 0xff, a0h1 = pk1 & 0xff;
    const int g0c0 = (pk0 >> 8) & 0xff, g0c1 = (pk1 >> 8) & 0xff;
    const int g1e0 = a0h0 + ((pk0 >> 16) & 0xff);
    const int g1e1 = a0h1 + ((pk1 >> 16) & 0xff);

    const int lr = lane & 15;
    const int q  = lane >> 4;

    // hoisted biases (L2-hot) and RK4 state prefetch (pair-split mapping)
    const int colA = ((2 * w) << 4) + lr;
    const int colB = ((2 * w + 1) << 4) + lr;
    float b2A0 = b2g[colA], b2A1 = b2g[128 + colA];
    float b2B0 = b2g[colB], b2B1 = b2g[128 + colB];

    const int p2    = tid >> 1;          // 0..127: (node, f) pair index
    const int half  = tid & 1;           // which half of the H-dot
    const int nodeW = p2 >> 6;
    const int fW    = p2 & 63;
    const int idx   = (b * N_ + n0 + nodeW) * F_ + fW;
    float ybase = Y[idx];
    float accv  = ACC[idx];              // garbage at r==0 (unused there)
    float b3v   = b3[fW];
    float dt = ts[t + 1] - ts[t];

    const float4_ fz = {0.f, 0.f, 0.f, 0.f};

    // ---- build hraw = bf16(relu(HS[sender,ty] + HRB[n,ty])), both nodes ----
    // (slots read directly: 512B/block, L2-hot, 4-lane broadcast — no staging)
    {
        int rbase = tid >> 2;          // 0..63  (slot within node)
        int c4    = tid & 3;
        #pragma unroll
        for (int it = 0; it < 2; it++) {
            int row  = (it << 6) | rbase;
            int sv   = slotsW[(b * N_ + n0 + it) * 64 + rbase];
            int a0h  = it ? a0h1 : a0h0;
            int ty   = (rbase >= a0h) ? 1 : 0;
            int srow = (sv < 0) ? 3200 : (b * N_ + sv);
            const unsigned short* gs = Gin + ((srow * 2 + ty) << 8);
            const unsigned short* gr = Gin + ((((b * N_ + n0 + it) * 2 + ty) << 8) + 128);
            #pragma unroll
            for (int j = 0; j < 4; j++) {
                int fo = (j << 5) + (c4 << 3);    // 64B-contiguous across c4
                short8 sv8 = *(const short8*)(gs + fo);
                short8 rv8 = *(const short8*)(gr + fo);
                float e0 = fmaxf(bf2f((unsigned short)sv8[0]) + bf2f((unsigned short)rv8[0]), 0.f);
                float e1 = fmaxf(bf2f((unsigned short)sv8[1]) + bf2f((unsigned short)rv8[1]), 0.f);
                float e2 = fmaxf(bf2f((unsigned short)sv8[2]) + bf2f((unsigned short)rv8[2]), 0.f);
                float e3 = fmaxf(bf2f((unsigned short)sv8[3]) + bf2f((unsigned short)rv8[3]), 0.f);
                float e4 = fmaxf(bf2f((unsigned short)sv8[4]) + bf2f((unsigned short)rv8[4]), 0.f);
                float e5 = fmaxf(bf2f((unsigned short)sv8[5]) + bf2f((unsigned short)rv8[5]), 0.f);
                float e6 = fmaxf(bf2f((unsigned short)sv8[6]) + bf2f((unsigned short)rv8[6]), 0.f);
                float e7 = fmaxf(bf2f((unsigned short)sv8[7]) + bf2f((unsigned short)rv8[7]), 0.f);
                uint4 hv;
                hv.x = cvtpk_bf16(e0, e1);
                hv.y = cvtpk_bf16(e2, e3);
                hv.z = cvtpk_bf16(e4, e5);
                hv.w = cvtpk_bf16(e6, e7);
                int off = (row << 8) | ((((j << 6) | (c4 << 4))) ^ ((row & 7) << 4));
                *(uint4*)((char*)hraw + off) = hv;
            }
        }
    }
    __syncthreads();   // hraw ready

    // ---- GEMM2: m = relu(h @ W2[k] + b2[k]), 8 row-tiles (both nodes) ----
    float4_ acc2[8][2];
    #pragma unroll
    for (int tt = 0; tt < 8; tt++) { acc2[tt][0] = fz; acc2[tt][1] = fz; }

    int ktile[8], lim[8];
    #pragma unroll
    for (int tt = 0; tt < 8; tt++) {
        int node = tt >> 2;
        int a0h  = node ? a0h1 : a0h0;
        ktile[tt] = (((tt & 3) << 4) >= a0h) ? 1 : 0;
        lim[tt]   = ktile[tt] ? (node ? g1e1 : g1e0) : (node ? g0c1 : g0c0);
    }

    {
        const short8* fb = (const short8*)w2f;   // chunk*64 + lane
        const int ctA = 2 * w, ctB = 2 * w + 1;
        #pragma unroll
        for (int kc = 0; kc < 4; kc++) {
            short8 B00 = fb[(((((ctA << 1) | 0) << 2) | kc) << 6) + lane];
            short8 B01 = fb[(((((ctA << 1) | 1) << 2) | kc) << 6) + lane];
            short8 B10 = fb[(((((ctB << 1) | 0) << 2) | kc) << 6) + lane];
            short8 B11 = fb[(((((ctB << 1) | 1) << 2) | kc) << 6) + lane];
            #pragma unroll
            for (int tt = 0; tt < 8; tt++) {
                int row = (tt << 4) + lr;
                int off = (row << 8) | ((((kc << 6) | (q << 4))) ^ ((row & 7) << 4));
                short8 a = *(const short8*)((const char*)hraw + off);
                short8 Bx0 = ktile[tt] ? B01 : B00;
                short8 Bx1 = ktile[tt] ? B11 : B10;
                acc2[tt][0] = __builtin_amdgcn_mfma_f32_16x16x32_bf16(a, Bx0, acc2[tt][0], 0, 0, 0);
                acc2[tt][1] = __builtin_amdgcn_mfma_f32_16x16x32_bf16(a, Bx1, acc2[tt][1], 0, 0, 0);
            }
        }
    }

    // epilogue: bias + relu, pad-mask, reduce over edges -> aggv
    float aggp[2][2] = {{0.f, 0.f}, {0.f, 0.f}};
    #pragma unroll
    for (int tt = 0; tt < 8; tt++) {
        int node = tt >> 2;
        #pragma unroll
        for (int cw = 0; cw < 2; cw++) {
            float bias = ktile[tt] ? (cw ? b2B1 : b2A1) : (cw ? b2B0 : b2A0);
            float p = 0.f;
            #pragma unroll
            for (int i = 0; i < 4; i++) {
                int jn = ((tt & 3) << 4) + (q << 2) + i;   // local edge row
                float mv = fmaxf(acc2[tt][cw][i] + bias, 0.f);
                p += (jn < lim[tt]) ? mv : 0.f;
            }
            p += __shfl_down(p, 32);
            p += __shfl_down(p, 16);
            aggp[node][cw] += p;   // valid on lanes 0..15
        }
    }
    if (lane < 16) {
        #pragma unroll
        for (int node = 0; node < 2; node++) {
            aggv[node][((2 * w)     << 4) + lane] = aggp[node][0];
            aggv[node][((2 * w + 1) << 4) + lane] = aggp[node][1];
        }
    }
    __syncthreads();   // aggv ready

    // ==== dy = tanh(agg*inv_n @ W3 + b3); RK4 stage update (pair-split) ====
    {
        const float4_* av = (const float4_*)(&aggv[nodeW][0]);
        float s = 0.f;
        #pragma unroll
        for (int c2 = 0; c2 < 8; c2++) {
            int c = (half << 3) | c2;
            short8 wv = *(const short8*)(w3f + (c << 9) + (fW << 3));
            float4_ a0v = av[2 * c], a1v = av[2 * c + 1];
            s += a0v[0] * bf2f((unsigned short)wv[0]);
            s += a0v[1] * bf2f((unsigned short)wv[1]);
            s += a0v[2] * bf2f((unsigned short)wv[2]);
            s += a0v[3] * bf2f((unsigned short)wv[3]);
            s += a1v[0] * bf2f((unsigned short)wv[4]);
            s += a1v[1] * bf2f((unsigned short)wv[5]);
            s += a1v[2] * bf2f((unsigned short)wv[6]);
            s += a1v[3] * bf2f((unsigned short)wv[7]);
        }
        s += __shfl_xor(s, 1);           // combine the two halves of the dot
        const float inv_n = 1.0f / (float)N_;
        float x = s * inv_n + b3v;
        float e = __expf(2.0f * x);
        float dy = 1.0f - 2.0f / (e + 1.0f);
        float ysv;
        if (r == 0)      { ysv = ybase + 0.5f * dt * dy; if (!half) ACC[idx] = dy; }
        else if (r == 1) { ysv = ybase + 0.5f * dt * dy; if (!half) ACC[idx] = accv + 2.f * dy; }
        else if (r == 2) { ysv = ybase + dt * dy;        if (!half) ACC[idx] = accv + 2.f * dy; }
        else {
            float yn = ybase + dt * (1.0f / 6.0f) * (accv + dy);
            ysv = yn;
            if (!half) {
                Y[idx] = yn;
                out[(b * N_ + n0 + nodeW) * (T_ * F_) + (t + 1) * F_ + fW] = yn;
            }
        }
        if (!half) ybnew[nodeW][fW] = f2bf(ysv);
    }
    __syncthreads();   // ybnew ready

    // ---- G-update for next eval: Gout rows of this block's 2 nodes ----
    {
        int arow = (lr < 2) ? lr : 0;     // A rows 0,1 = nodes n0,n0+1
        short8 a0v = *(const short8*)(&ybnew[arow][q << 3]);
        short8 a1v = *(const short8*)(&ybnew[arow][32 + (q << 3)]);
        #pragma unroll
        for (int ct = 0; ct < 8; ct++) {
            int c  = (w << 3) | ct;
            int c0 = c << 4;
            short8 bb0 = *(const short8*)(wcf + (c << 10) + (lane << 3));
            short8 bb1 = *(const short8*)(wcf + (c << 10) + 512 + (lane << 3));
            float4_ ag = fz;
            ag = __builtin_amdgcn_mfma_f32_16x16x32_bf16(a0v, bb0, ag, 0, 0, 0);
            ag = __builtin_amdgcn_mfma_f32_16x16x32_bf16(a1v, bb1, ag, 0, 0, 0);
            if (q == 0) {   // C rows 0,1 live in q==0, i=0,1
                int ty = c0 >> 8, inner = c0 & 255, part = inner >> 7;
                float bias = part ? b1g[(ty << 7) + (inner & 127) + lr] : 0.f;
                int gbase = (((b * N_ + n0) * 2 + ty) << 8) + (part << 7) + (inner & 127) + lr;
                Gout[gbase]       = f2bf(ag[0] + bias);
                Gout[gbase + 512] = f2bf(ag[1] + bias);
            }
        }
    }
}

// ---------------------------------------------------------------------------
extern "C" void kernel_launch(void* const* d_in, const int* in_sizes, int n_in,
                              void* d_out, int out_size, void* d_ws, size_t ws_size,
                              hipStream_t stream) {
    const float* fp    = (const float*)d_in[0];   // first_point [1,3200,64]
    const float* ts    = (const float*)d_in[1];   // time_steps [40]
    const int*   graph = (const int*)  d_in[2];   // [64,2450]
    const float* W1    = (const float*)d_in[3];   // [2,128,128]
    const float* b1    = (const float*)d_in[4];   // [2,128]
    const float* W2    = (const float*)d_in[5];   // [2,128,128]
    const float* b2    = (const float*)d_in[6];   // [2,128]
    const float* W3    = (const float*)d_in[7];   // [128,64]
    const float* b3    = (const float*)d_in[8];   // [64]
    float* out = (float*)d_out;

    char* ws = (char*)d_ws;
    size_t off = 0;
    auto alloc = [&](size_t bytes) {
        void* p = ws + off;
        off = (off + bytes + 255) & ~(size_t)255;
        return p;
    };
    float*          Y    = (float*)alloc(204800 * 4);
    float*          ACC  = (float*)alloc(204800 * 4);
    unsigned short* yb0  = (unsigned short*)alloc(204800 * 2);
    unsigned short* w2f  = (unsigned short*)alloc(32768 * 2);
    unsigned short* wcf  = (unsigned short*)alloc(32768 * 2);
    unsigned short* w3f  = (unsigned short*)alloc(8192 * 2);
    int*            slots = (int*)alloc(3200 * 64 * 4);
    int*            a0w   = (int*)alloc(3200 * 4);
    unsigned short* G0   = (unsigned short*)alloc(3201 * 512 * 2);   // 3.28 MB
    unsigned short* G1   = (unsigned short*)alloc(3201 * 512 * 2);

    k_w2f <<<128, 256, 0, stream>>>(W2, w2f);
    k_wcf <<<128, 256, 0, stream>>>(W1, wcf);
    k_w3f <<<32,  256, 0, stream>>>(W3, w3f);
    k_sort<<<13,  256, 0, stream>>>(graph, slots, a0w);
    k_init<<<800, 256, 0, stream>>>(fp, Y, yb0, out);
    k_ginit<<<201, 256, 0, stream>>>(yb0, wcf, b1, G0, G1);

    unsigned short* gin = G0; unsigned short* gout = G1;
    for (int s = 0; s < T_ - 1; s++) {
        for (int rr = 0; rr < 4; rr++) {
            k_eval<<<EVAL_BLOCKS, 256, 0, stream>>>(gin, gout, Y, ACC, slots, a0w,
                                                    w2f, b2, w3f, b3, wcf, b1,
                                                    ts, out, s, rr);
            unsigned short* tmp = gin; gin = gout; gout = tmp;
        }
    }
}

// Round 14
// 3870.330 us; speedup vs baseline: 1.0660x; 1.0660x over previous
//
#include <hip/hip_runtime.h>

// Problem constants (DiffeqSolver: S=1, b=64, N=50, F=64, H=128, K=2, T=40)
#define B_   64
#define N_   50
#define F_   64
#define H_   128
#define T_   40
#define E_   2450      // N*(N-1)
#define EPN  49        // edges per receiving node
#define NGRP 25        // node-groups per batch (2 nodes each)
#define EVAL_BLOCKS (B_ * NGRP)   // 1600

typedef __attribute__((ext_vector_type(8))) short  short8;   // 8 x bf16 (4 VGPRs)
typedef __attribute__((ext_vector_type(4))) float  float4_;  // MFMA accumulator

__device__ __forceinline__ unsigned short f2bf(float x) {
    union { float f; unsigned u; } v; v.f = x;
    unsigned r = v.u + 0x7fffu + ((v.u >> 16) & 1u);   // round-to-nearest-even
    return (unsigned short)(r >> 16);
}
__device__ __forceinline__ float bf2f(unsigned short x) {
    union { unsigned u; float f; } v; v.u = ((unsigned)x) << 16;
    return v.f;
}
// HW pack: 2 f32 -> 2 bf16 (RNE), one VALU op (no builtin on gfx950; verified
// numerically identical to manual f2bf pair in round 8 — absmax unchanged)
__device__ __forceinline__ unsigned cvtpk_bf16(float lo, float hi) {
    unsigned r;
    asm("v_cvt_pk_bf16_f32 %0, %1, %2" : "=v"(r) : "v"(lo), "v"(hi));
    return r;
}

// ---------------------------------------------------------------------------
// Setup: w2f = W2 in MFMA-fragment order (1KB contiguous per wave fragment).
// ---------------------------------------------------------------------------
__global__ void k_w2f(const float* __restrict__ W2, unsigned short* __restrict__ w2f) {
    int tid = blockIdx.x * 256 + threadIdx.x;   // 0 .. 32767
    int chunk = tid >> 9, lane = (tid >> 3) & 63, e = tid & 7;
    int ctile = chunk >> 3, ty = (chunk >> 2) & 1, kc = chunk & 3;
    int i = (kc << 5) + ((lane >> 4) << 3) + e;     // W2 row (k)
    int j = (ctile << 4) + (lane & 15);             // W2 col
    w2f[tid] = f2bf(W2[(((ty << 7) | i) << 7) | j]);
}

// Setup: wcf = W1-concat in fragment order (for G production).
__global__ void k_wcf(const float* __restrict__ W1, unsigned short* __restrict__ wcf) {
    int tid = blockIdx.x * 256 + threadIdx.x;   // 0 .. 32767
    int chunk2 = tid >> 9, lane = (tid >> 3) & 63, e = tid & 7;
    int c = chunk2 >> 1, h = chunk2 & 1;
    int col = (c << 4) + (lane & 15);
    int kk  = (h << 5) + ((lane >> 4) << 3) + e;
    int t = col >> 8, part = (col >> 7) & 1, hcol = col & 127;
    wcf[tid] = f2bf(W1[((t << 7) + (part << 6) + kk) * 128 + hcol]);
}

// Setup: w3f[c][f][e] = bf16(W3[c*8+e][f])
__global__ void k_w3f(const float* __restrict__ W3, unsigned short* __restrict__ w3f) {
    int tid = blockIdx.x * 256 + threadIdx.x;   // 0 .. 8191
    int c = tid >> 9, f = (tid >> 3) & 63, e = tid & 7;
    w3f[tid] = f2bf(W3[(((c << 3) + e) << 6) | f]);
}

// ---------------------------------------------------------------------------
// Setup: per (b, n): counting-sort the 49 senders by edge type.
// ---------------------------------------------------------------------------
__global__ void k_sort(const int* __restrict__ graph, int* __restrict__ slots,
                       int* __restrict__ a0w) {
    int tid = blockIdx.x * 256 + threadIdx.x;
    if (tid >= B_ * N_) return;
    int b = tid / N_, n = tid % N_;
    const int* g = graph + b * E_ + n * EPN;
    int base = tid * 64;
    for (int j = 0; j < 64; j++) slots[base + j] = -1;
    int g0 = 0;
    for (int j = 0; j < EPN; j++) g0 += (g[j] == 0);
    int a0 = (g0 + 15) & ~15;
    int g1 = EPN - g0;
    a0w[tid] = a0 | (g0 << 8) | (g1 << 16);
    int p0 = 0, p1 = a0;
    for (int j = 0; j < EPN; j++) {
        int s = (j < n) ? j : j + 1;        // sender index (skip self-loop)
        if (g[j] == 0) slots[base + (p0++)] = s;
        else           slots[base + (p1++)] = s;
    }
}

// ---------------------------------------------------------------------------
// Setup: Y = first_point (f32 state), yb0 = bf16 mirror, out[:, t=0, :] = y0
// ---------------------------------------------------------------------------
__global__ void k_init(const float* __restrict__ fp, float* __restrict__ Y,
                       unsigned short* __restrict__ yb0, float* __restrict__ out) {
    int tid = blockIdx.x * 256 + threadIdx.x;   // 0 .. 204799
    float v = fp[tid];
    Y[tid] = v;
    yb0[tid] = f2bf(v);
    int bn = tid >> 6, f = tid & 63;
    out[bn * (T_ * F_) + f] = v;
}

// ---------------------------------------------------------------------------
// One-time: G0[node][t][0:128]=HS, [128:256]=HRB (+b1), from yb0.  bf16.
// G layout: ((node*2 + t) * 256 + idx) bf16; node 3200 = zero pad row.
// ---------------------------------------------------------------------------
__global__ void k_ginit(const unsigned short* __restrict__ yb0,
                        const unsigned short* __restrict__ wcf,
                        const float* __restrict__ b1g,
                        unsigned short* __restrict__ G0, unsigned short* __restrict__ G1) {
    int blk = blockIdx.x, tid = threadIdx.x;
    if (blk == 200) {
        for (int i = tid; i < 512; i += 256) {
            G0[3200 * 512 + i] = 0;
            G1[3200 * 512 + i] = 0;
        }
        return;
    }
    int lane = tid & 63, w = tid >> 6, lr = lane & 15, q = lane >> 4;
    int n0 = blk * 16;
    short8 a0v = *(const short8*)(yb0 + (n0 + lr) * 64 + (q << 3));
    short8 a1v = *(const short8*)(yb0 + (n0 + lr) * 64 + 32 + (q << 3));
    const float4_ fz = {0.f, 0.f, 0.f, 0.f};
    #pragma unroll
    for (int ct = 0; ct < 8; ct++) {
        int c  = (w << 3) | ct;              // col-tile 0..31
        int c0 = c << 4;
        short8 bb0 = *(const short8*)(wcf + (c << 10) + (lane << 3));
        short8 bb1 = *(const short8*)(wcf + (c << 10) + 512 + (lane << 3));
        float4_ ag = fz;
        ag = __builtin_amdgcn_mfma_f32_16x16x32_bf16(a0v, bb0, ag, 0, 0, 0);
        ag = __builtin_amdgcn_mfma_f32_16x16x32_bf16(a1v, bb1, ag, 0, 0, 0);
        int ty = c0 >> 8, inner = c0 & 255, part = inner >> 7;
        float bias = part ? b1g[(ty << 7) + (inner & 127) + lr] : 0.f;
        int gbase = (((n0 + (q << 2)) * 2 + ty) << 8) + (part << 7) + (inner & 127) + lr;
        #pragma unroll
        for (int i = 0; i < 4; i++)
            G0[gbase + i * 512] = f2bf(ag[i] + bias);
    }
}

// ---------------------------------------------------------------------------
// One ODE eval + RK4 stage update. Block = (batch b, nodes n0, n0+1).
// VERIFIED BEST (round 11: 3905 us total): build hraw[128 rows] (both nodes)
// -> GEMM2 (8 tiles) -> agg -> W3/RK4 -> G-update.  4 barriers.
// G stored bf16.  h-pack uses HW v_cvt_pk_bf16_f32 (verified, round 8).
//
// Measured-dead alternatives (do NOT revisit):
//  * persistent kernel w/ grid.sync or agent-fence barrier: 46 GB L2-inval
//    HBM refetch, 40-70 ms (rounds 7 & 10).  Kernel launches ARE the cheap
//    cross-XCD sync on MI355X.
//  * dropping slt staging / pair-splitting W3 phase: +1.4 us/eval (round 12,
//    prologue load pressure delays the critical G-gather).
//  * two-sequential-half hraw (higher occupancy): slower (round 5).
//  * f32 G / cvt_pk in build: flat (round 8).
//
// blockIdx remap: batch b pinned to XCD b%8.
// ---------------------------------------------------------------------------
__launch_bounds__(256, 4)
__global__ void k_eval(const unsigned short* __restrict__ Gin,
                       unsigned short* __restrict__ Gout,
                       float* __restrict__ Y, float* __restrict__ ACC,
                       const int* __restrict__ slotsW, const int* __restrict__ a0W,
                       const unsigned short* __restrict__ w2f,
                       const float* __restrict__ b2g,
                       const unsigned short* __restrict__ w3f, const float* __restrict__ b3,
                       const unsigned short* __restrict__ wcf, const float* __restrict__ b1g,
                       const float* __restrict__ ts, float* __restrict__ out,
                       int t, int r) {
    // hraw: 128 rows x 128 bf16, XOR-swizzled (byte ^= (row&7)<<4)
    __shared__ __align__(16) unsigned short hraw[128 * 128];   // 32 KiB
    __shared__ int   slt[2][64];
    __shared__ float aggv[2][128];
    __shared__ __align__(16) unsigned short ybnew[2][64];

    const int tid  = threadIdx.x;
    const int lane = tid & 63;
    const int w    = tid >> 6;
    const int blk  = blockIdx.x;
    const int xcd  = blk & 7;
    const int jj   = blk >> 3;               // 0..199
    const int b    = xcd + ((jj / NGRP) << 3);
    const int n0   = (jj % NGRP) * 2;

    if (tid < 128) slt[tid >> 6][tid & 63] =
        slotsW[(b * N_ + n0 + (tid >> 6)) * 64 + (tid & 63)];

    int pk0 = a0W[b * N_ + n0], pk1 = a0W[b * N_ + n0 + 1];
    const int a0h0 = pk0 & 0xff, a0h1 = pk1 & 0xff;
    const int g0c0 = (pk0 >> 8) & 0xff, g0c1 = (pk1 >> 8) & 0xff;
    const int g1e0 = a0h0 + ((pk0 >> 16) & 0xff);
    const int g1e1 = a0h1 + ((pk1 >> 16) & 0xff);

    const int lr = lane & 15;
    const int q  = lane >> 4;

    // hoisted biases (L2-hot) and RK4 state prefetch
    const int colA = ((2 * w) << 4) + lr;
    const int colB = ((2 * w + 1) << 4) + lr;
    float b2A0 = b2g[colA], b2A1 = b2g[128 + colA];
    float b2B0 = b2g[colB], b2B1 = b2g[128 + colB];

    float ybase = 0.f, accv = 0.f, b3v = 0.f;
    int idx = 0;
    if (tid < 128) {
        idx   = (b * N_ + n0 + (tid >> 6)) * F_ + (tid & 63);
        ybase = Y[idx];
        accv  = ACC[idx];          // garbage at r==0 (unused there)
        b3v   = b3[tid & 63];
    }
    float dt = ts[t + 1] - ts[t];

    const float4_ fz = {0.f, 0.f, 0.f, 0.f};

    __syncthreads();   // slt visible

    // ---- build hraw = bf16(relu(HS[sender,ty] + HRB[n,ty])), both nodes ----
    {
        int rbase = tid >> 2;          // 0..63  (slot within node)
        int c4    = tid & 3;
        #pragma unroll
        for (int it = 0; it < 2; it++) {
            int row  = (it << 6) | rbase;
            int sv   = slt[it][rbase];
            int a0h  = it ? a0h1 : a0h0;
            int ty   = (rbase >= a0h) ? 1 : 0;
            int srow = (sv < 0) ? 3200 : (b * N_ + sv);
            const unsigned short* gs = Gin + ((srow * 2 + ty) << 8);
            const unsigned short* gr = Gin + ((((b * N_ + n0 + it) * 2 + ty) << 8) + 128);
            #pragma unroll
            for (int j = 0; j < 4; j++) {
                int fo = (j << 5) + (c4 << 3);    // 64B-contiguous across c4
                short8 sv8 = *(const short8*)(gs + fo);
                short8 rv8 = *(const short8*)(gr + fo);
                float e0 = fmaxf(bf2f((unsigned short)sv8[0]) + bf2f((unsigned short)rv8[0]), 0.f);
                float e1 = fmaxf(bf2f((unsigned short)sv8[1]) + bf2f((unsigned short)rv8[1]), 0.f);
                float e2 = fmaxf(bf2f((unsigned short)sv8[2]) + bf2f((unsigned short)rv8[2]), 0.f);
                float e3 = fmaxf(bf2f((unsigned short)sv8[3]) + bf2f((unsigned short)rv8[3]), 0.f);
                float e4 = fmaxf(bf2f((unsigned short)sv8[4]) + bf2f((unsigned short)rv8[4]), 0.f);
                float e5 = fmaxf(bf2f((unsigned short)sv8[5]) + bf2f((unsigned short)rv8[5]), 0.f);
                float e6 = fmaxf(bf2f((unsigned short)sv8[6]) + bf2f((unsigned short)rv8[6]), 0.f);
                float e7 = fmaxf(bf2f((unsigned short)sv8[7]) + bf2f((unsigned short)rv8[7]), 0.f);
                uint4 hv;
                hv.x = cvtpk_bf16(e0, e1);
                hv.y = cvtpk_bf16(e2, e3);
                hv.z = cvtpk_bf16(e4, e5);
                hv.w = cvtpk_bf16(e6, e7);
                int off = (row << 8) | ((((j << 6) | (c4 << 4))) ^ ((row & 7) << 4));
                *(uint4*)((char*)hraw + off) = hv;
            }
        }
    }
    __syncthreads();   // hraw ready

    // ---- GEMM2: m = relu(h @ W2[k] + b2[k]), 8 row-tiles (both nodes) ----
    float4_ acc2[8][2];
    #pragma unroll
    for (int tt = 0; tt < 8; tt++) { acc2[tt][0] = fz; acc2[tt][1] = fz; }

    int ktile[8], lim[8];
    #pragma unroll
    for (int tt = 0; tt < 8; tt++) {
        int node = tt >> 2;
        int a0h  = node ? a0h1 : a0h0;
        ktile[tt] = (((tt & 3) << 4) >= a0h) ? 1 : 0;
        lim[tt]   = ktile[tt] ? (node ? g1e1 : g1e0) : (node ? g0c1 : g0c0);
    }

    {
        const short8* fb = (const short8*)w2f;   // chunk*64 + lane
        const int ctA = 2 * w, ctB = 2 * w + 1;
        #pragma unroll
        for (int kc = 0; kc < 4; kc++) {
            short8 B00 = fb[(((((ctA << 1) | 0) << 2) | kc) << 6) + lane];
            short8 B01 = fb[(((((ctA << 1) | 1) << 2) | kc) << 6) + lane];
            short8 B10 = fb[(((((ctB << 1) | 0) << 2) | kc) << 6) + lane];
            short8 B11 = fb[(((((ctB << 1) | 1) << 2) | kc) << 6) + lane];
            #pragma unroll
            for (int tt = 0; tt < 8; tt++) {
                int row = (tt << 4) + lr;
                int off = (row << 8) | ((((kc << 6) | (q << 4))) ^ ((row & 7) << 4));
                short8 a = *(const short8*)((const char*)hraw + off);
                short8 Bx0 = ktile[tt] ? B01 : B00;
                short8 Bx1 = ktile[tt] ? B11 : B10;
                acc2[tt][0] = __builtin_amdgcn_mfma_f32_16x16x32_bf16(a, Bx0, acc2[tt][0], 0, 0, 0);
                acc2[tt][1] = __builtin_amdgcn_mfma_f32_16x16x32_bf16(a, Bx1, acc2[tt][1], 0, 0, 0);
            }
        }
    }

    // epilogue: bias + relu, pad-mask, reduce over edges -> aggv
    float aggp[2][2] = {{0.f, 0.f}, {0.f, 0.f}};
    #pragma unroll
    for (int tt = 0; tt < 8; tt++) {
        int node = tt >> 2;
        #pragma unroll
        for (int cw = 0; cw < 2; cw++) {
            float bias = ktile[tt] ? (cw ? b2B1 : b2A1) : (cw ? b2B0 : b2A0);
            float p = 0.f;
            #pragma unroll
            for (int i = 0; i < 4; i++) {
                int jn = ((tt & 3) << 4) + (q << 2) + i;   // local edge row
                float mv = fmaxf(acc2[tt][cw][i] + bias, 0.f);
                p += (jn < lim[tt]) ? mv : 0.f;
            }
            p += __shfl_down(p, 32);
            p += __shfl_down(p, 16);
            aggp[node][cw] += p;   // valid on lanes 0..15
        }
    }
    if (lane < 16) {
        #pragma unroll
        for (int node = 0; node < 2; node++) {
            aggv[node][((2 * w)     << 4) + lane] = aggp[node][0];
            aggv[node][((2 * w + 1) << 4) + lane] = aggp[node][1];
        }
    }
    __syncthreads();   // aggv ready

    // ============ dy = tanh(agg*inv_n @ W3 + b3); RK4 stage update ==========
    if (tid < 128) {
        int node = tid >> 6, f = tid & 63;
        int n = n0 + node;
        const float4_* av = (const float4_*)(&aggv[node][0]);
        float s = 0.f;
        #pragma unroll
        for (int c = 0; c < 16; c++) {
            short8 wv = *(const short8*)(w3f + (c << 9) + (f << 3));  // 1KB/wave
            float4_ a0v = av[2 * c], a1v = av[2 * c + 1];
            s += a0v[0] * bf2f((unsigned short)wv[0]);
            s += a0v[1] * bf2f((unsigned short)wv[1]);
            s += a0v[2] * bf2f((unsigned short)wv[2]);
            s += a0v[3] * bf2f((unsigned short)wv[3]);
            s += a1v[0] * bf2f((unsigned short)wv[4]);
            s += a1v[1] * bf2f((unsigned short)wv[5]);
            s += a1v[2] * bf2f((unsigned short)wv[6]);
            s += a1v[3] * bf2f((unsigned short)wv[7]);
        }
        const float inv_n = 1.0f / (float)N_;
        float x = s * inv_n + b3v;
        float e = __expf(2.0f * x);
        float dy = 1.0f - 2.0f / (e + 1.0f);
        float ysv;
        if (r == 0)      { ACC[idx] = dy;               ysv = ybase + 0.5f * dt * dy; }
        else if (r == 1) { ACC[idx] = accv + 2.f * dy;  ysv = ybase + 0.5f * dt * dy; }
        else if (r == 2) { ACC[idx] = accv + 2.f * dy;  ysv = ybase + dt * dy; }
        else {
            float af = accv + dy;
            float yn = ybase + dt * (1.0f / 6.0f) * af;
            Y[idx] = yn;
            out[(b * N_ + n) * (T_ * F_) + (t + 1) * F_ + f] = yn;
            ysv = yn;
        }
        ybnew[node][f] = f2bf(ysv);
    }
    __syncthreads();   // ybnew ready

    // ---- G-update for next eval: Gout rows of this block's 2 nodes ----
    {
        int arow = (lr < 2) ? lr : 0;     // A rows 0,1 = nodes n0,n0+1
        short8 a0v = *(const short8*)(&ybnew[arow][q << 3]);
        short8 a1v = *(const short8*)(&ybnew[arow][32 + (q << 3)]);
        #pragma unroll
        for (int ct = 0; ct < 8; ct++) {
            int c  = (w << 3) | ct;
            int c0 = c << 4;
            short8 bb0 = *(const short8*)(wcf + (c << 10) + (lane << 3));
            short8 bb1 = *(const short8*)(wcf + (c << 10) + 512 + (lane << 3));
            float4_ ag = fz;
            ag = __builtin_amdgcn_mfma_f32_16x16x32_bf16(a0v, bb0, ag, 0, 0, 0);
            ag = __builtin_amdgcn_mfma_f32_16x16x32_bf16(a1v, bb1, ag, 0, 0, 0);
            if (q == 0) {   // C rows 0,1 live in q==0, i=0,1
                int ty = c0 >> 8, inner = c0 & 255, part = inner >> 7;
                float bias = part ? b1g[(ty << 7) + (inner & 127) + lr] : 0.f;
                int gbase = (((b * N_ + n0) * 2 + ty) << 8) + (part << 7) + (inner & 127) + lr;
                Gout[gbase]       = f2bf(ag[0] + bias);
                Gout[gbase + 512] = f2bf(ag[1] + bias);
            }
        }
    }
}

// ---------------------------------------------------------------------------
extern "C" void kernel_launch(void* const* d_in, const int* in_sizes, int n_in,
                              void* d_out, int out_size, void* d_ws, size_t ws_size,
                              hipStream_t stream) {
    const float* fp    = (const float*)d_in[0];   // first_point [1,3200,64]
    const float* ts    = (const float*)d_in[1];   // time_steps [40]
    const int*   graph = (const int*)  d_in[2];   // [64,2450]
    const float* W1    = (const float*)d_in[3];   // [2,128,128]
    const float* b1    = (const float*)d_in[4];   // [2,128]
    const float* W2    = (const float*)d_in[5];   // [2,128,128]
    const float* b2    = (const float*)d_in[6];   // [2,128]
    const float* W3    = (const float*)d_in[7];   // [128,64]
    const float* b3    = (const float*)d_in[8];   // [64]
    float* out = (float*)d_out;

    char* ws = (char*)d_ws;
    size_t off = 0;
    auto alloc = [&](size_t bytes) {
        void* p = ws + off;
        off = (off + bytes + 255) & ~(size_t)255;
        return p;
    };
    float*          Y    = (float*)alloc(204800 * 4);
    float*          ACC  = (float*)alloc(204800 * 4);
    unsigned short* yb0  = (unsigned short*)alloc(204800 * 2);
    unsigned short* w2f  = (unsigned short*)alloc(32768 * 2);
    unsigned short* wcf  = (unsigned short*)alloc(32768 * 2);
    unsigned short* w3f  = (unsigned short*)alloc(8192 * 2);
    int*            slots = (int*)alloc(3200 * 64 * 4);
    int*            a0w   = (int*)alloc(3200 * 4);
    unsigned short* G0   = (unsigned short*)alloc(3201 * 512 * 2);   // 3.28 MB
    unsigned short* G1   = (unsigned short*)alloc(3201 * 512 * 2);

    k_w2f <<<128, 256, 0, stream>>>(W2, w2f);
    k_wcf <<<128, 256, 0, stream>>>(W1, wcf);
    k_w3f <<<32,  256, 0, stream>>>(W3, w3f);
    k_sort<<<13,  256, 0, stream>>>(graph, slots, a0w);
    k_init<<<800, 256, 0, stream>>>(fp, Y, yb0, out);
    k_ginit<<<201, 256, 0, stream>>>(yb0, wcf, b1, G0, G1);

    unsigned short* gin = G0; unsigned short* gout = G1;
    for (int s = 0; s < T_ - 1; s++) {
        for (int rr = 0; rr < 4; rr++) {
            k_eval<<<EVAL_BLOCKS, 256, 0, stream>>>(gin, gout, Y, ACC, slots, a0w,
                                                    w2f, b2, w3f, b3, wcf, b1,
                                                    ts, out, s, rr);
            unsigned short* tmp = gin; gin = gout; gout = tmp;
        }
    }
}